// Round 14
// baseline (103.489 us; speedup 1.0000x reference)
//
#include <hip/hip_runtime.h>
#include <hip/hip_bf16.h>

typedef __attribute__((ext_vector_type(8))) short bf16x8;
typedef __attribute__((ext_vector_type(4))) float f32x4;

#define NTOK   2048
#define NEXP   16
#define NF     512
#define NH     1024
#define NCOUT  512
#define NPAIR  8192   // NTOK * 4
#define MAXPAN 80     // sum ceil(cnt_e/128) <= 8192/128 + 16

__device__ __forceinline__ void gload16_lds(const __hip_bfloat16* g, const __hip_bfloat16* l) {
  __builtin_amdgcn_global_load_lds((const __attribute__((address_space(1))) void*)g,
                                   (__attribute__((address_space(3))) void*)l, 16, 0, 0);
}

// ---------------- mega-prep: router (blocks 0..2047) + W transposes (2048..10239) ----------------
__global__ __launch_bounds__(256) void prep_kernel(
    const float* __restrict__ h, const float* __restrict__ W_mu,
    const float* __restrict__ b_mu, const float* __restrict__ W_logvar,
    const float* __restrict__ b_logvar,
    int* __restrict__ topk_idx, float* __restrict__ topk_w,
    __hip_bfloat16* __restrict__ hb,
    const float* __restrict__ W1, __hip_bfloat16* __restrict__ W1t,
    const float* __restrict__ W2, __hip_bfloat16* __restrict__ W2t)
{
  __shared__ float smem[64 * 33];
  __shared__ float smu[NEXP], svar[NEXP];
  const int tid = threadIdx.x;

  if (blockIdx.x < NTOK) {
    // ---------------- router ----------------
    float* hs  = smem;
    float* hs2 = smem + NF;
    const int b = blockIdx.x;
    for (int i = tid; i < NF; i += 256) {
      float v = h[(size_t)b * NF + i];
      hs[i] = v; hs2[i] = v * v;
      hb[(size_t)b * NF + i] = __float2bfloat16(v);
    }
    __syncthreads();
    const int e = tid >> 4, l = tid & 15;
    float mu = 0.f, var = 0.f;
    const float4* wm4 = (const float4*)(W_mu + e * NF);
    const float4* wv4 = (const float4*)(W_logvar + e * NF);
    const float4* h4  = (const float4*)hs;
    const float4* h24 = (const float4*)hs2;
#pragma unroll
    for (int j = 0; j < NF / 64; ++j) {
      int i4 = l + j * 16;
      float4 a = h4[i4],  wa = wm4[i4];
      float4 c = h24[i4], wc = wv4[i4];
      mu  += a.x * wa.x + a.y * wa.y + a.z * wa.z + a.w * wa.w;
      var += c.x * __expf(wc.x) + c.y * __expf(wc.y) + c.z * __expf(wc.z) + c.w * __expf(wc.w);
    }
#pragma unroll
    for (int o = 1; o < 16; o <<= 1) { mu += __shfl_xor(mu, o); var += __shfl_xor(var, o); }
    if (l == 0) { smu[e] = mu + b_mu[e]; svar[e] = var + __expf(b_logvar[e]); }
    __syncthreads();
    if (tid < 64) {
      float val = -1e30f;
      if (tid < NEXP) {
        float v = fmaxf(svar[tid], 1e-12f);
        val = smu[tid] / sqrtf(1.0f + 0.39269908169872414f * v);  // pi/8
      }
      float mx = 0.f, wsum = 0.f;
      int i0, i1, i2, i3; float p0, p1, p2, p3;
#define TOPK_ROUND(ii, pp, FIRST)                                          \
      {                                                                    \
        float m = val;                                                     \
        m = fmaxf(m, __shfl_xor(m, 1));  m = fmaxf(m, __shfl_xor(m, 2));   \
        m = fmaxf(m, __shfl_xor(m, 4));  m = fmaxf(m, __shfl_xor(m, 8));   \
        m = fmaxf(m, __shfl_xor(m, 16)); m = fmaxf(m, __shfl_xor(m, 32));  \
        unsigned long long bm = __ballot(val == m);                        \
        int bi = (int)__builtin_ctzll(bm);                                 \
        if (FIRST) mx = m;                                                 \
        pp = expf(m - mx); wsum += pp; ii = bi;                            \
        if (tid == bi) val = -1e30f;                                       \
      }
      TOPK_ROUND(i0, p0, 1)
      TOPK_ROUND(i1, p1, 0)
      TOPK_ROUND(i2, p2, 0)
      TOPK_ROUND(i3, p3, 0)
#undef TOPK_ROUND
      if (tid == 0) {
        float inv = 1.0f / fmaxf(wsum, 1e-12f);
        topk_idx[b * 4 + 0] = i0; topk_w[b * 4 + 0] = p0 * inv;
        topk_idx[b * 4 + 1] = i1; topk_w[b * 4 + 1] = p1 * inv;
        topk_idx[b * 4 + 2] = i2; topk_w[b * 4 + 2] = p2 * inv;
        topk_idx[b * 4 + 3] = i3; topk_w[b * 4 + 3] = p3 * inv;
      }
    }
  } else {
    // ---------------- weight transpose+convert ----------------
    const int bid = blockIdx.x - NTOK;
    const float* in; __hip_bfloat16* out; int R, C, e, cx, ry;
    if (bid < 4096) {
      in = W1; out = W1t; R = NF; C = NH;
      e = bid >> 8; cx = bid & 31; ry = (bid >> 5) & 7;
    } else {
      in = W2; out = W2t; R = NH; C = NCOUT;
      const int b2 = bid - 4096;
      e = b2 >> 8; cx = b2 & 15; ry = (b2 >> 4) & 15;
    }
    float (*tile)[33] = (float (*)[33])smem;
    const int r0 = ry * 64, c0 = cx * 32;
    const int x = tid & 31, y = tid >> 5;
    const float* ip = in + ((size_t)e * R + r0) * C + c0;
#pragma unroll
    for (int i = 0; i < 8; ++i) tile[y + 8 * i][x] = ip[(size_t)(y + 8 * i) * C + x];
    __syncthreads();
    const int rp = tid & 31, cb = tid >> 5;
#pragma unroll
    for (int j = 0; j < 4; ++j) {
      const int c = cb + 8 * j;
      union { __hip_bfloat16 b[2]; unsigned u; } v;
      v.b[0] = __float2bfloat16(tile[2 * rp][c]);
      v.b[1] = __float2bfloat16(tile[2 * rp + 1][c]);
      *(unsigned*)(out + ((size_t)e * C + c0 + c) * R + r0 + 2 * rp) = v.u;
    }
  }
}

// ---------------- fused count + prefix + stable scatter + panel worklist (8 blocks) ----------------
// pinfo[2p] = (e<<16)|row0 (global row), pinfo[2p+1] = rows in panel; sentinel 0xFFFFFFFF.
__global__ __launch_bounds__(1024) void route_finish_kernel(
    const int* __restrict__ topk_idx,
    int* __restrict__ token_of_row, int* __restrict__ pair_row,
    unsigned* __restrict__ pinfo)
{
  __shared__ int cnt[128][16];
  __shared__ int choff[128][2];
  __shared__ int tot[16];
  __shared__ int soff[16];
  const int tid = threadIdx.x;
  const int wv = tid >> 6, ln = tid & 63;
  const int e0 = blockIdx.x * 2;
  int mye[8], myrank[8];
#pragma unroll
  for (int r = 0; r < 8; ++r) {
    const int chunk = r * 16 + wv;
    const int t = chunk * 64 + ln;
    const int e = topk_idx[t];
    mye[r] = e;
    unsigned long long mymask = 0;
#pragma unroll
    for (int ee = 0; ee < 16; ++ee) {
      unsigned long long bmask = __ballot(e == ee);
      if (ln == 0) cnt[chunk][ee] = __popcll(bmask);
      if (e == ee) mymask = bmask;
    }
    myrank[r] = __popcll(mymask & ((1ull << ln) - 1ull));
  }
  __syncthreads();
  if (tid < 16) {
    int run = 0;
    for (int c = 0; c < 128; ++c) run += cnt[c][tid];
    tot[tid] = run;
  }
  if (tid >= 32 && tid < 34) {
    const int e = e0 + (tid - 32);
    int run = 0;
    for (int c = 0; c < 128; ++c) { choff[c][tid - 32] = run; run += cnt[c][e]; }
  }
  __syncthreads();
  if (tid == 0) {
    int run = 0;
    for (int e2 = 0; e2 < NEXP; ++e2) { soff[e2] = run; run += tot[e2]; }
    if (blockIdx.x == 0) {
      int np = 0;
      for (int e2 = 0; e2 < NEXP; ++e2) {
        for (int r0 = 0; r0 < tot[e2]; r0 += 128) {
          pinfo[2 * np]     = ((unsigned)e2 << 16) | (unsigned)(soff[e2] + r0);
          pinfo[2 * np + 1] = (unsigned)((tot[e2] - r0 < 128) ? (tot[e2] - r0) : 128);
          ++np;
        }
      }
      for (; np < MAXPAN; ++np) pinfo[2 * np] = 0xFFFFFFFFu;
    }
  }
  __syncthreads();
#pragma unroll
  for (int r = 0; r < 8; ++r) {
    const int e = mye[r];
    if (e == e0 || e == e0 + 1) {
      const int chunk = r * 16 + wv;
      const int t = chunk * 64 + ln;
      const int pos = soff[e] + choff[chunk][e - e0] + myrank[r];
      token_of_row[pos] = t >> 2;
      pair_row[t] = pos;
    }
  }
}

// ================= 128x64 grouped GEMM, single-buffer, coalesced+XOR staging =================

// ---------------- GEMM1: a = relu(h @ W1 + b1), panel worklist ----------------
__global__ __launch_bounds__(256) void gemm1_kernel(
    const __hip_bfloat16* __restrict__ hb,   // [NTOK, NF]
    const __hip_bfloat16* __restrict__ W1t,  // [E, NH, NF]  (n-major)
    const float* __restrict__ b1,            // [E, NH]
    const int* __restrict__ token_of_row,
    const unsigned* __restrict__ pinfo,
    __hip_bfloat16* __restrict__ a_out)      // [NPAIR, NH]
{
  const int bid = blockIdx.x;                       // 1280 blocks
  const int id  = (bid & 7) * 160 + (bid >> 3);     // XCD-chunked
  const int p   = id >> 4;
  const unsigned pw = pinfo[2 * p];
  if (pw == 0xFFFFFFFFu) return;
  const int e    = (int)(pw >> 16);
  const int row0 = (int)(pw & 0xFFFFu);
  const int rows = (int)pinfo[2 * p + 1];
  const int n0   = (id & 15) * 64;

  __shared__ __align__(16) __hip_bfloat16 As[128 * 64];
  __shared__ __align__(16) __hip_bfloat16 Bs[64 * 64];

  const int tid = threadIdx.x;
  const int w = tid >> 6, l = tid & 63;
  const int wm = w >> 1, wn = w & 1;
  const int r16 = l & 15, g4 = l >> 4;
  const int sx = r16 & 7;
  const int koffL = (((l & 7) ^ (l >> 3)) * 8);    // pre-swizzled k-seg

  const __hip_bfloat16* Aptr[4];
#pragma unroll
  for (int i = 0; i < 4; ++i) {
    int r = row0 + w * 32 + i * 8 + (l >> 3);
    if (r > NPAIR - 1) r = NPAIR - 1;
    Aptr[i] = hb + (size_t)token_of_row[r] * NF + koffL;
  }
  const __hip_bfloat16* Bptr[2];
#pragma unroll
  for (int i = 0; i < 2; ++i)
    Bptr[i] = W1t + ((size_t)e * NH + n0 + w * 16 + i * 8 + (l >> 3)) * NF + koffL;

  f32x4 acc[4][2] = {};

  for (int k0 = 0; k0 < NF; k0 += 64) {
    __syncthreads();
#pragma unroll
    for (int i = 0; i < 4; ++i) gload16_lds(Aptr[i] + k0, As + (w * 32 + i * 8) * 64);
#pragma unroll
    for (int i = 0; i < 2; ++i) gload16_lds(Bptr[i] + k0, Bs + (w * 16 + i * 8) * 64);
    __syncthreads();
#pragma unroll
    for (int ks = 0; ks < 2; ++ks) {
      const int seg = (ks * 4 + g4) ^ sx;
      bf16x8 af[4], bq[2];
#pragma unroll
      for (int rr = 0; rr < 4; ++rr)
        af[rr] = *(const bf16x8*)(As + (wm * 64 + rr * 16 + r16) * 64 + seg * 8);
#pragma unroll
      for (int nn = 0; nn < 2; ++nn)
        bq[nn] = *(const bf16x8*)(Bs + (wn * 32 + nn * 16 + r16) * 64 + seg * 8);
#pragma unroll
      for (int rr = 0; rr < 4; ++rr)
#pragma unroll
        for (int nn = 0; nn < 2; ++nn)
          acc[rr][nn] = __builtin_amdgcn_mfma_f32_16x16x32_bf16(af[rr], bq[nn], acc[rr][nn], 0, 0, 0);
    }
  }

  const int q4 = l >> 4, cl = l & 15;
#pragma unroll
  for (int rr = 0; rr < 4; ++rr) {
#pragma unroll
    for (int nn = 0; nn < 2; ++nn) {
      const int c = n0 + wn * 32 + nn * 16 + cl;
      const float bias = b1[e * NH + c];
#pragma unroll
      for (int q = 0; q < 4; ++q) {
        const int r = wm * 64 + rr * 16 + q4 * 4 + q;
        if (r < rows) {
          float v = fmaxf(acc[rr][nn][q] + bias, 0.f);
          a_out[(size_t)(row0 + r) * NH + c] = __float2bfloat16(v);
        }
      }
    }
  }
}

// ---------------- GEMM2: ybuf(bf16) = a @ W2 + b2, panel worklist ----------------
__global__ __launch_bounds__(256) void gemm2_kernel(
    const __hip_bfloat16* __restrict__ a_in,  // [NPAIR, NH]
    const __hip_bfloat16* __restrict__ W2t,   // [E, NCOUT, NH] (n-major)
    const float* __restrict__ b2,             // [E, NCOUT]
    const unsigned* __restrict__ pinfo,
    __hip_bfloat16* __restrict__ ybuf)        // [NPAIR, NCOUT] bf16
{
  const int bid = blockIdx.x;                       // 640 blocks
  const int id  = (bid & 7) * 80 + (bid >> 3);      // XCD-chunked
  const int p   = id >> 3;
  const unsigned pw = pinfo[2 * p];
  if (pw == 0xFFFFFFFFu) return;
  const int e    = (int)(pw >> 16);
  const int row0 = (int)(pw & 0xFFFFu);
  const int rows = (int)pinfo[2 * p + 1];
  const int n0   = (id & 7) * 64;

  __shared__ __align__(16) __hip_bfloat16 As[128 * 64];
  __shared__ __align__(16) __hip_bfloat16 Bs[64 * 64];

  const int tid = threadIdx.x;
  const int w = tid >> 6, l = tid & 63;
  const int wm = w >> 1, wn = w & 1;
  const int r16 = l & 15, g4 = l >> 4;
  const int sx = r16 & 7;
  const int koffL = (((l & 7) ^ (l >> 3)) * 8);

  const __hip_bfloat16* Aptr[4];
#pragma unroll
  for (int i = 0; i < 4; ++i) {
    int r = row0 + w * 32 + i * 8 + (l >> 3);
    if (r > NPAIR - 1) r = NPAIR - 1;
    Aptr[i] = a_in + (size_t)r * NH + koffL;
  }
  const __hip_bfloat16* Bptr[2];
#pragma unroll
  for (int i = 0; i < 2; ++i)
    Bptr[i] = W2t + ((size_t)e * NCOUT + n0 + w * 16 + i * 8 + (l >> 3)) * NH + koffL;

  f32x4 acc[4][2] = {};

  for (int k0 = 0; k0 < NH; k0 += 64) {
    __syncthreads();
#pragma unroll
    for (int i = 0; i < 4; ++i) gload16_lds(Aptr[i] + k0, As + (w * 32 + i * 8) * 64);
#pragma unroll
    for (int i = 0; i < 2; ++i) gload16_lds(Bptr[i] + k0, Bs + (w * 16 + i * 8) * 64);
    __syncthreads();
#pragma unroll
    for (int ks = 0; ks < 2; ++ks) {
      const int seg = (ks * 4 + g4) ^ sx;
      bf16x8 af[4], bq[2];
#pragma unroll
      for (int rr = 0; rr < 4; ++rr)
        af[rr] = *(const bf16x8*)(As + (wm * 64 + rr * 16 + r16) * 64 + seg * 8);
#pragma unroll
      for (int nn = 0; nn < 2; ++nn)
        bq[nn] = *(const bf16x8*)(Bs + (wn * 32 + nn * 16 + r16) * 64 + seg * 8);
#pragma unroll
      for (int rr = 0; rr < 4; ++rr)
#pragma unroll
        for (int nn = 0; nn < 2; ++nn)
          acc[rr][nn] = __builtin_amdgcn_mfma_f32_16x16x32_bf16(af[rr], bq[nn], acc[rr][nn], 0, 0, 0);
    }
  }

  const int q4 = l >> 4, cl = l & 15;
#pragma unroll
  for (int rr = 0; rr < 4; ++rr) {
#pragma unroll
    for (int nn = 0; nn < 2; ++nn) {
      const int c = n0 + wn * 32 + nn * 16 + cl;
      const float bias = b2[e * NCOUT + c];
#pragma unroll
      for (int q = 0; q < 4; ++q) {
        const int r = wm * 64 + rr * 16 + q4 * 4 + q;
        if (r < rows)
          ybuf[(size_t)(row0 + r) * NCOUT + c] = __float2bfloat16(acc[rr][nn][q] + bias);
      }
    }
  }
}

// ---------------- combine: out[tok] = sum_k w_k * ybuf[pair_row[tok*4+k]] ----------------
__global__ __launch_bounds__(256) void combine_kernel(
    const __hip_bfloat16* __restrict__ ybuf, const int* __restrict__ pair_row,
    const float* __restrict__ topk_w, float* __restrict__ out)
{
  const int tok = blockIdx.x;
  const int c = threadIdx.x * 2;
  float a0 = 0.f, a1 = 0.f;
#pragma unroll
  for (int k = 0; k < 4; ++k) {
    const int t = tok * 4 + k;
    const float wt = topk_w[t];
    const unsigned u = *(const unsigned*)(ybuf + (size_t)pair_row[t] * NCOUT + c);
    a0 += wt * __uint_as_float((u & 0xFFFFu) << 16);
    a1 += wt * __uint_as_float(u & 0xFFFF0000u);
  }
  *(float2*)(out + (size_t)tok * NCOUT + c) = make_float2(a0, a1);
}

extern "C" void kernel_launch(void* const* d_in, const int* in_sizes, int n_in,
                              void* d_out, int out_size, void* d_ws, size_t ws_size,
                              hipStream_t stream) {
  (void)in_sizes; (void)n_in; (void)ws_size; (void)out_size;
  const float* h        = (const float*)d_in[0];
  const float* W_mu     = (const float*)d_in[1];
  const float* b_mu     = (const float*)d_in[2];
  const float* W_logvar = (const float*)d_in[3];
  const float* b_logvar = (const float*)d_in[4];
  const float* W1       = (const float*)d_in[5];
  const float* b1       = (const float*)d_in[6];
  const float* W2       = (const float*)d_in[7];
  const float* b2       = (const float*)d_in[8];
  float* out = (float*)d_out;

  char* p = (char*)d_ws;
  unsigned* pinfo = (unsigned*)p; p += 2 * MAXPAN * 4;
  p += 64; // pad
  int*   topk_idx = (int*)p;   p += (size_t)NPAIR * 4;
  float* topk_w   = (float*)p; p += (size_t)NPAIR * 4;
  int*   tok_row  = (int*)p;   p += (size_t)NPAIR * 4;
  int*   pair_row = (int*)p;   p += (size_t)NPAIR * 4;
  __hip_bfloat16* hb   = (__hip_bfloat16*)p; p += (size_t)NTOK * NF * 2;
  __hip_bfloat16* W1t  = (__hip_bfloat16*)p; p += (size_t)NEXP * NF * NH * 2;
  __hip_bfloat16* W2t  = (__hip_bfloat16*)p; p += (size_t)NEXP * NH * NCOUT * 2;
  __hip_bfloat16* abuf = (__hip_bfloat16*)p; p += (size_t)NPAIR * NH * 2;
  __hip_bfloat16* ybuf = (__hip_bfloat16*)p; p += (size_t)NPAIR * NCOUT * 2;

  prep_kernel<<<NTOK + 8192, 256, 0, stream>>>(h, W_mu, b_mu, W_logvar, b_logvar,
                                               topk_idx, topk_w, hb, W1, W1t, W2, W2t);
  route_finish_kernel<<<8, 1024, 0, stream>>>(topk_idx, tok_row, pair_row, pinfo);

  gemm1_kernel<<<1280, 256, 0, stream>>>(hb, W1t, b1, tok_row, pinfo, abuf);
  gemm2_kernel<<<640, 256, 0, stream>>>(abuf, W2t, b2, pinfo, ybuf);
  combine_kernel<<<NTOK, 256, 0, stream>>>(ybuf, pair_row, topk_w, out);
}

// Round 15
// 87.101 us; speedup vs baseline: 1.1882x; 1.1882x over previous
//
#include <hip/hip_runtime.h>
#include <hip/hip_bf16.h>

typedef __attribute__((ext_vector_type(8))) short bf16x8;
typedef __attribute__((ext_vector_type(4))) float f32x4;

#define NTOK   2048
#define NEXP   16
#define NF     512
#define NH     1024
#define NCOUT  512
#define NPAIR  8192   // NTOK * 4

__device__ __forceinline__ void gload16_lds(const __hip_bfloat16* g, const __hip_bfloat16* l) {
  __builtin_amdgcn_global_load_lds((const __attribute__((address_space(1))) void*)g,
                                   (__attribute__((address_space(3))) void*)l, 16, 0, 0);
}

// ---------------- mega-prep: router (blocks 0..2047) + W transposes (2048..10239) ----------------
__global__ __launch_bounds__(256) void prep_kernel(
    const float* __restrict__ h, const float* __restrict__ W_mu,
    const float* __restrict__ b_mu, const float* __restrict__ W_logvar,
    const float* __restrict__ b_logvar,
    int* __restrict__ topk_idx, float* __restrict__ topk_w,
    __hip_bfloat16* __restrict__ hb,
    const float* __restrict__ W1, __hip_bfloat16* __restrict__ W1t,
    const float* __restrict__ W2, __hip_bfloat16* __restrict__ W2t)
{
  __shared__ float smem[64 * 33];
  __shared__ float smu[NEXP], svar[NEXP];
  const int tid = threadIdx.x;

  if (blockIdx.x < NTOK) {
    // ---------------- router ----------------
    float* hs  = smem;
    float* hs2 = smem + NF;
    const int b = blockIdx.x;
    for (int i = tid; i < NF; i += 256) {
      float v = h[(size_t)b * NF + i];
      hs[i] = v; hs2[i] = v * v;
      hb[(size_t)b * NF + i] = __float2bfloat16(v);
    }
    __syncthreads();
    const int e = tid >> 4, l = tid & 15;
    float mu = 0.f, var = 0.f;
    const float4* wm4 = (const float4*)(W_mu + e * NF);
    const float4* wv4 = (const float4*)(W_logvar + e * NF);
    const float4* h4  = (const float4*)hs;
    const float4* h24 = (const float4*)hs2;
#pragma unroll
    for (int j = 0; j < NF / 64; ++j) {
      int i4 = l + j * 16;
      float4 a = h4[i4],  wa = wm4[i4];
      float4 c = h24[i4], wc = wv4[i4];
      mu  += a.x * wa.x + a.y * wa.y + a.z * wa.z + a.w * wa.w;
      var += c.x * __expf(wc.x) + c.y * __expf(wc.y) + c.z * __expf(wc.z) + c.w * __expf(wc.w);
    }
#pragma unroll
    for (int o = 1; o < 16; o <<= 1) { mu += __shfl_xor(mu, o); var += __shfl_xor(var, o); }
    if (l == 0) { smu[e] = mu + b_mu[e]; svar[e] = var + __expf(b_logvar[e]); }
    __syncthreads();
    if (tid < 64) {
      float val = -1e30f;
      if (tid < NEXP) {
        float v = fmaxf(svar[tid], 1e-12f);
        val = smu[tid] / sqrtf(1.0f + 0.39269908169872414f * v);  // pi/8
      }
      float mx = 0.f, wsum = 0.f;
      int i0, i1, i2, i3; float p0, p1, p2, p3;
#define TOPK_ROUND(ii, pp, FIRST)                                          \
      {                                                                    \
        float m = val;                                                     \
        m = fmaxf(m, __shfl_xor(m, 1));  m = fmaxf(m, __shfl_xor(m, 2));   \
        m = fmaxf(m, __shfl_xor(m, 4));  m = fmaxf(m, __shfl_xor(m, 8));   \
        m = fmaxf(m, __shfl_xor(m, 16)); m = fmaxf(m, __shfl_xor(m, 32));  \
        unsigned long long bm = __ballot(val == m);                        \
        int bi = (int)__builtin_ctzll(bm);                                 \
        if (FIRST) mx = m;                                                 \
        pp = expf(m - mx); wsum += pp; ii = bi;                            \
        if (tid == bi) val = -1e30f;                                       \
      }
      TOPK_ROUND(i0, p0, 1)
      TOPK_ROUND(i1, p1, 0)
      TOPK_ROUND(i2, p2, 0)
      TOPK_ROUND(i3, p3, 0)
#undef TOPK_ROUND
      if (tid == 0) {
        float inv = 1.0f / fmaxf(wsum, 1e-12f);
        topk_idx[b * 4 + 0] = i0; topk_w[b * 4 + 0] = p0 * inv;
        topk_idx[b * 4 + 1] = i1; topk_w[b * 4 + 1] = p1 * inv;
        topk_idx[b * 4 + 2] = i2; topk_w[b * 4 + 2] = p2 * inv;
        topk_idx[b * 4 + 3] = i3; topk_w[b * 4 + 3] = p3 * inv;
      }
    }
  } else {
    // ---------------- weight transpose+convert ----------------
    const int bid = blockIdx.x - NTOK;
    const float* in; __hip_bfloat16* out; int R, C, e, cx, ry;
    if (bid < 4096) {
      in = W1; out = W1t; R = NF; C = NH;
      e = bid >> 8; cx = bid & 31; ry = (bid >> 5) & 7;
    } else {
      in = W2; out = W2t; R = NH; C = NCOUT;
      const int b2 = bid - 4096;
      e = b2 >> 8; cx = b2 & 15; ry = (b2 >> 4) & 15;
    }
    float (*tile)[33] = (float (*)[33])smem;
    const int r0 = ry * 64, c0 = cx * 32;
    const int x = tid & 31, y = tid >> 5;
    const float* ip = in + ((size_t)e * R + r0) * C + c0;
#pragma unroll
    for (int i = 0; i < 8; ++i) tile[y + 8 * i][x] = ip[(size_t)(y + 8 * i) * C + x];
    __syncthreads();
    const int rp = tid & 31, cb = tid >> 5;
#pragma unroll
    for (int j = 0; j < 4; ++j) {
      const int c = cb + 8 * j;
      union { __hip_bfloat16 b[2]; unsigned u; } v;
      v.b[0] = __float2bfloat16(tile[2 * rp][c]);
      v.b[1] = __float2bfloat16(tile[2 * rp + 1][c]);
      *(unsigned*)(out + ((size_t)e * C + c0 + c) * R + r0 + 2 * rp) = v.u;
    }
  }
}

// ---------------- fused count + prefix + stable scatter (8 blocks) ----------------
__global__ __launch_bounds__(1024) void route_finish_kernel(
    const int* __restrict__ topk_idx,
    int* __restrict__ counts, int* __restrict__ offsets,
    int* __restrict__ token_of_row, int* __restrict__ pair_row)
{
  __shared__ int cnt[128][16];
  __shared__ int choff[128][2];
  __shared__ int tot[16];
  __shared__ int soff[16];
  const int tid = threadIdx.x;
  const int wv = tid >> 6, ln = tid & 63;
  const int e0 = blockIdx.x * 2;
  int mye[8], myrank[8];
#pragma unroll
  for (int r = 0; r < 8; ++r) {
    const int chunk = r * 16 + wv;
    const int t = chunk * 64 + ln;
    const int e = topk_idx[t];
    mye[r] = e;
    unsigned long long mymask = 0;
#pragma unroll
    for (int ee = 0; ee < 16; ++ee) {
      unsigned long long bmask = __ballot(e == ee);
      if (ln == 0) cnt[chunk][ee] = __popcll(bmask);
      if (e == ee) mymask = bmask;
    }
    myrank[r] = __popcll(mymask & ((1ull << ln) - 1ull));
  }
  __syncthreads();
  if (tid < 16) {
    int run = 0;
    for (int c = 0; c < 128; ++c) run += cnt[c][tid];
    tot[tid] = run;
    if (blockIdx.x == 0) counts[tid] = run;
  }
  if (tid >= 32 && tid < 34) {
    const int e = e0 + (tid - 32);
    int run = 0;
    for (int c = 0; c < 128; ++c) { choff[c][tid - 32] = run; run += cnt[c][e]; }
  }
  __syncthreads();
  if (tid == 0) {
    int run = 0;
    for (int e2 = 0; e2 < NEXP; ++e2) {
      soff[e2] = run;
      if (blockIdx.x == 0) offsets[e2] = run;
      run += tot[e2];
    }
  }
  __syncthreads();
#pragma unroll
  for (int r = 0; r < 8; ++r) {
    const int e = mye[r];
    if (e == e0 || e == e0 + 1) {
      const int chunk = r * 16 + wv;
      const int t = chunk * 64 + ln;
      const int pos = soff[e] + choff[chunk][e - e0] + myrank[r];
      token_of_row[pos] = t >> 2;
      pair_row[t] = pos;
    }
  }
}

// ================= 128x64 grouped GEMM, single-buffer, coalesced+XOR staging =================

// ---------------- GEMM1: a = relu(h @ W1 + b1) ----------------
__global__ __launch_bounds__(256) void gemm1_kernel(
    const __hip_bfloat16* __restrict__ hb,   // [NTOK, NF]
    const __hip_bfloat16* __restrict__ W1t,  // [E, NH, NF]  (n-major)
    const float* __restrict__ b1,            // [E, NH]
    const int* __restrict__ token_of_row, const int* __restrict__ offsets,
    const int* __restrict__ counts,
    __hip_bfloat16* __restrict__ a_out)      // [NPAIR, NH]
{
  const int bid = blockIdx.x;                      // 4096 blocks
  const int id  = (bid & 7) * 512 + (bid >> 3);    // XCD-chunked
  const int e   = id >> 8;
  const int m0  = ((id >> 4) & 15) * 128;
  const int n0  = (id & 15) * 64;
  const int cnt = counts[e];
  if (m0 >= cnt) return;
  const int off = offsets[e];

  __shared__ __align__(16) __hip_bfloat16 As[128 * 64];
  __shared__ __align__(16) __hip_bfloat16 Bs[64 * 64];

  const int tid = threadIdx.x;
  const int w = tid >> 6, l = tid & 63;
  const int wm = w >> 1, wn = w & 1;
  const int r16 = l & 15, g4 = l >> 4;
  const int sx = r16 & 7;
  const int koffL = (((l & 7) ^ (l >> 3)) * 8);    // pre-swizzled k-seg

  const __hip_bfloat16* Aptr[4];
#pragma unroll
  for (int i = 0; i < 4; ++i) {
    int r = off + m0 + w * 32 + i * 8 + (l >> 3);
    if (r > NPAIR - 1) r = NPAIR - 1;
    Aptr[i] = hb + (size_t)token_of_row[r] * NF + koffL;
  }
  const __hip_bfloat16* Bptr[2];
#pragma unroll
  for (int i = 0; i < 2; ++i)
    Bptr[i] = W1t + ((size_t)e * NH + n0 + w * 16 + i * 8 + (l >> 3)) * NF + koffL;

  f32x4 acc[4][2] = {};

  for (int k0 = 0; k0 < NF; k0 += 64) {
    __syncthreads();
#pragma unroll
    for (int i = 0; i < 4; ++i) gload16_lds(Aptr[i] + k0, As + (w * 32 + i * 8) * 64);
#pragma unroll
    for (int i = 0; i < 2; ++i) gload16_lds(Bptr[i] + k0, Bs + (w * 16 + i * 8) * 64);
    __syncthreads();
#pragma unroll
    for (int ks = 0; ks < 2; ++ks) {
      const int seg = (ks * 4 + g4) ^ sx;
      bf16x8 af[4], bq[2];
#pragma unroll
      for (int rr = 0; rr < 4; ++rr)
        af[rr] = *(const bf16x8*)(As + (wm * 64 + rr * 16 + r16) * 64 + seg * 8);
#pragma unroll
      for (int nn = 0; nn < 2; ++nn)
        bq[nn] = *(const bf16x8*)(Bs + (wn * 32 + nn * 16 + r16) * 64 + seg * 8);
#pragma unroll
      for (int rr = 0; rr < 4; ++rr)
#pragma unroll
        for (int nn = 0; nn < 2; ++nn)
          acc[rr][nn] = __builtin_amdgcn_mfma_f32_16x16x32_bf16(af[rr], bq[nn], acc[rr][nn], 0, 0, 0);
    }
  }

  const int q4 = l >> 4, cl = l & 15;
  const int mmax = cnt - m0;
#pragma unroll
  for (int rr = 0; rr < 4; ++rr) {
#pragma unroll
    for (int nn = 0; nn < 2; ++nn) {
      const int c = n0 + wn * 32 + nn * 16 + cl;
      const float bias = b1[e * NH + c];
#pragma unroll
      for (int q = 0; q < 4; ++q) {
        const int r = wm * 64 + rr * 16 + q4 * 4 + q;
        if (r < mmax) {
          float v = fmaxf(acc[rr][nn][q] + bias, 0.f);
          a_out[(size_t)(off + m0 + r) * NH + c] = __float2bfloat16(v);
        }
      }
    }
  }
}

// ---------------- GEMM2: ybuf = a @ W2 + b2 (K=1024, plain f32 stores) ----------------
__global__ __launch_bounds__(256) void gemm2_kernel(
    const __hip_bfloat16* __restrict__ a_in,  // [NPAIR, NH]
    const __hip_bfloat16* __restrict__ W2t,   // [E, NCOUT, NH] (n-major)
    const float* __restrict__ b2,             // [E, NCOUT]
    const int* __restrict__ offsets, const int* __restrict__ counts,
    float* __restrict__ ybuf)                 // [NPAIR, NCOUT]
{
  const int bid = blockIdx.x;                      // 2048 blocks
  const int id  = (bid & 7) * 256 + (bid >> 3);    // XCD-chunked
  const int e   = id >> 7;
  const int m0  = ((id >> 3) & 15) * 128;
  const int n0  = (id & 7) * 64;
  const int cnt = counts[e];
  if (m0 >= cnt) return;
  const int off = offsets[e];

  __shared__ __align__(16) __hip_bfloat16 As[128 * 64];
  __shared__ __align__(16) __hip_bfloat16 Bs[64 * 64];

  const int tid = threadIdx.x;
  const int w = tid >> 6, l = tid & 63;
  const int wm = w >> 1, wn = w & 1;
  const int r16 = l & 15, g4 = l >> 4;
  const int sx = r16 & 7;
  const int koffL = (((l & 7) ^ (l >> 3)) * 8);

  const __hip_bfloat16* Aptr[4];
#pragma unroll
  for (int i = 0; i < 4; ++i) {
    int r = off + m0 + w * 32 + i * 8 + (l >> 3);
    if (r > NPAIR - 1) r = NPAIR - 1;
    Aptr[i] = a_in + (size_t)r * NH + koffL;
  }
  const __hip_bfloat16* Bptr[2];
#pragma unroll
  for (int i = 0; i < 2; ++i)
    Bptr[i] = W2t + ((size_t)e * NCOUT + n0 + w * 16 + i * 8 + (l >> 3)) * NH + koffL;

  f32x4 acc[4][2] = {};

  for (int k0 = 0; k0 < NH; k0 += 64) {
    __syncthreads();
#pragma unroll
    for (int i = 0; i < 4; ++i) gload16_lds(Aptr[i] + k0, As + (w * 32 + i * 8) * 64);
#pragma unroll
    for (int i = 0; i < 2; ++i) gload16_lds(Bptr[i] + k0, Bs + (w * 16 + i * 8) * 64);
    __syncthreads();
#pragma unroll
    for (int ks = 0; ks < 2; ++ks) {
      const int seg = (ks * 4 + g4) ^ sx;
      bf16x8 af[4], bq[2];
#pragma unroll
      for (int rr = 0; rr < 4; ++rr)
        af[rr] = *(const bf16x8*)(As + (wm * 64 + rr * 16 + r16) * 64 + seg * 8);
#pragma unroll
      for (int nn = 0; nn < 2; ++nn)
        bq[nn] = *(const bf16x8*)(Bs + (wn * 32 + nn * 16 + r16) * 64 + seg * 8);
#pragma unroll
      for (int rr = 0; rr < 4; ++rr)
#pragma unroll
        for (int nn = 0; nn < 2; ++nn)
          acc[rr][nn] = __builtin_amdgcn_mfma_f32_16x16x32_bf16(af[rr], bq[nn], acc[rr][nn], 0, 0, 0);
    }
  }

  const int q4 = l >> 4, cl = l & 15;
  const int mmax = cnt - m0;
#pragma unroll
  for (int rr = 0; rr < 4; ++rr) {
#pragma unroll
    for (int nn = 0; nn < 2; ++nn) {
      const int c = n0 + wn * 32 + nn * 16 + cl;
      const float bias = b2[e * NCOUT + c];
#pragma unroll
      for (int q = 0; q < 4; ++q) {
        const int r = wm * 64 + rr * 16 + q4 * 4 + q;
        if (r < mmax)
          ybuf[(size_t)(off + m0 + r) * NCOUT + c] = acc[rr][nn][q] + bias;
      }
    }
  }
}

// ---------------- combine: out[tok] = sum_k w_k * ybuf[pair_row[tok*4+k]] ----------------
__global__ __launch_bounds__(256) void combine_kernel(
    const float* __restrict__ ybuf, const int* __restrict__ pair_row,
    const float* __restrict__ topk_w, float* __restrict__ out)
{
  const int tok = blockIdx.x;
  const int c = threadIdx.x * 2;
  float a0 = 0.f, a1 = 0.f;
#pragma unroll
  for (int k = 0; k < 4; ++k) {
    const int t = tok * 4 + k;
    const float wt = topk_w[t];
    const float2 y = *(const float2*)(ybuf + (size_t)pair_row[t] * NCOUT + c);
    a0 += wt * y.x; a1 += wt * y.y;
  }
  *(float2*)(out + (size_t)tok * NCOUT + c) = make_float2(a0, a1);
}

extern "C" void kernel_launch(void* const* d_in, const int* in_sizes, int n_in,
                              void* d_out, int out_size, void* d_ws, size_t ws_size,
                              hipStream_t stream) {
  (void)in_sizes; (void)n_in; (void)ws_size; (void)out_size;
  const float* h        = (const float*)d_in[0];
  const float* W_mu     = (const float*)d_in[1];
  const float* b_mu     = (const float*)d_in[2];
  const float* W_logvar = (const float*)d_in[3];
  const float* b_logvar = (const float*)d_in[4];
  const float* W1       = (const float*)d_in[5];
  const float* b1       = (const float*)d_in[6];
  const float* W2       = (const float*)d_in[7];
  const float* b2       = (const float*)d_in[8];
  float* out = (float*)d_out;

  char* p = (char*)d_ws;
  int*   counts   = (int*)p;   p += 16 * 4;
  int*   offsets  = (int*)p;   p += 16 * 4;
  p += 32 * 4; // pad
  int*   topk_idx = (int*)p;   p += (size_t)NPAIR * 4;
  float* topk_w   = (float*)p; p += (size_t)NPAIR * 4;
  int*   tok_row  = (int*)p;   p += (size_t)NPAIR * 4;
  int*   pair_row = (int*)p;   p += (size_t)NPAIR * 4;
  __hip_bfloat16* hb   = (__hip_bfloat16*)p; p += (size_t)NTOK * NF * 2;
  __hip_bfloat16* W1t  = (__hip_bfloat16*)p; p += (size_t)NEXP * NF * NH * 2;
  __hip_bfloat16* W2t  = (__hip_bfloat16*)p; p += (size_t)NEXP * NH * NCOUT * 2;
  __hip_bfloat16* abuf = (__hip_bfloat16*)p; p += (size_t)NPAIR * NH * 2;
  float*          ybuf = (float*)p;          p += (size_t)NPAIR * NCOUT * 4;

  prep_kernel<<<NTOK + 8192, 256, 0, stream>>>(h, W_mu, b_mu, W_logvar, b_logvar,
                                               topk_idx, topk_w, hb, W1, W1t, W2, W2t);
  route_finish_kernel<<<8, 1024, 0, stream>>>(topk_idx, counts, offsets, tok_row, pair_row);

  gemm1_kernel<<<4096, 256, 0, stream>>>(hb, W1t, b1, tok_row, offsets, counts, abuf);
  gemm2_kernel<<<2048, 256, 0, stream>>>(abuf, W2t, b2, offsets, counts, ybuf);
  combine_kernel<<<NTOK, 256, 0, stream>>>(ybuf, pair_row, topk_w, out);
}